// Round 1
// baseline (21.930 us; speedup 1.0000x reference)
//
#include <hip/hip_runtime.h>
#include <math.h>

// RoI pooling: fm [2,56,56,256] f32, rois [2,48,4] f32 (x, y_max, w, h),
// out [2,48,7,7,256] f32.
// One workgroup (256 threads) per output bin: blockIdx.x enumerates
// (b,r,i,j); threadIdx.x = channel. Channel axis is contiguous, so each
// (y,x) read by the block is one coalesced 1 KB transaction.

#define NB 2
#define NR 48
#define FH 56
#define FW 56
#define NC 256
#define PH 7
#define PW 7

__global__ __launch_bounds__(256) void roi_pool_kernel(
    const float* __restrict__ fm, const float* __restrict__ rois,
    float* __restrict__ out) {
  int bin = blockIdx.x;            // ((b*NR + r)*PH + i)*PW + j
  const int c = threadIdx.x;

  const int j = bin % PW; bin /= PW;
  const int i = bin % PH; bin /= PH;
  const int r = bin % NR;
  const int b = bin / NR;

  const float* roi = rois + (b * NR + r) * 4;
  const float x = roi[0], y = roi[1], w = roi[2], h = roi[3];

  // Match JAX reference fp32 arithmetic + trunc-to-int32 exactly.
  const int w_start = (int)(56.0f * x);
  const int w_end   = (int)(56.0f * (x + w));
  const int h_start = (int)(56.0f * (1.0f - y));
  const int h_end   = (int)(56.0f * (1.0f - y + h));
  const int rh = h_end - h_start;
  const int rw = w_end - w_start;
  const int h_step = rh / PH;
  const int w_step = rw / PW;

  const int r0 = h_start + i * h_step;
  const int r1 = (i == PH - 1) ? (h_start + rh) : (r0 + h_step);
  const int c0 = w_start + j * w_step;
  const int c1 = (j == PW - 1) ? (w_start + rw) : (c0 + w_step);

  float m = -INFINITY;
  const float* base = fm + ((size_t)b * FH * FW) * NC + c;
  for (int yy = r0; yy < r1; ++yy) {
    const float* rowp = base + (size_t)yy * FW * NC;
    for (int xx = c0; xx < c1; ++xx) {
      m = fmaxf(m, rowp[(size_t)xx * NC]);
    }
  }

  out[(size_t)blockIdx.x * NC + c] = m;
}

extern "C" void kernel_launch(void* const* d_in, const int* in_sizes, int n_in,
                              void* d_out, int out_size, void* d_ws, size_t ws_size,
                              hipStream_t stream) {
  const float* fm   = (const float*)d_in[0];
  const float* rois = (const float*)d_in[1];
  float* out = (float*)d_out;
  const int nbins = NB * NR * PH * PW;  // 4704
  roi_pool_kernel<<<nbins, 256, 0, stream>>>(fm, rois, out);
}

// Round 2
// 20.478 us; speedup vs baseline: 1.0709x; 1.0709x over previous
//
#include <hip/hip_runtime.h>
#include <math.h>

// RoI pooling: fm [2,56,56,256] f32, rois [2,48,4] f32 (x, y_max, w, h),
// out [2,48,7,7,256] f32.
//
// One WAVE (64 lanes) per output bin; lane l holds channels 4l..4l+3 as a
// float4. Each (y,x) pixel read is one global_load_dwordx4 per lane =
// 1 KB/wave fully-coalesced transaction. 4 bins per 256-thread block.

#define NB 2
#define NR 48
#define FH 56
#define FW 56
#define NC 256
#define PH 7
#define PW 7
#define NBINS (NB * NR * PH * PW)   // 4704

__global__ __launch_bounds__(256) void roi_pool_kernel(
    const float4* __restrict__ fm4, const float* __restrict__ rois,
    float4* __restrict__ out4) {
  const int wave = threadIdx.x >> 6;          // 0..3
  const int lane = threadIdx.x & 63;          // channel group
  int bin = blockIdx.x * 4 + wave;            // ((b*NR + r)*PH + i)*PW + j
  if (bin >= NBINS) return;
  const int obin = bin;

  const int j = bin % PW; bin /= PW;
  const int i = bin % PH; bin /= PH;
  const int r = bin % NR;
  const int b = bin / NR;

  const float* roi = rois + (b * NR + r) * 4;
  const float x = roi[0], y = roi[1], w = roi[2], h = roi[3];

  // Match JAX reference fp32 arithmetic + trunc-to-int32 exactly.
  const int w_start = (int)(56.0f * x);
  const int w_end   = (int)(56.0f * (x + w));
  const int h_start = (int)(56.0f * (1.0f - y));
  const int h_end   = (int)(56.0f * (1.0f - y + h));
  const int rh = h_end - h_start;
  const int rw = w_end - w_start;
  const int h_step = rh / PH;
  const int w_step = rw / PW;

  const int r0 = h_start + i * h_step;
  const int r1 = (i == PH - 1) ? (h_start + rh) : (r0 + h_step);
  const int c0 = w_start + j * w_step;
  const int c1 = (j == PW - 1) ? (w_start + rw) : (c0 + w_step);

  // fm4 layout: [(b*FH + y)*FW + x] * 64 + lane  (64 float4 per pixel)
  float4 m = make_float4(-INFINITY, -INFINITY, -INFINITY, -INFINITY);
  const float4* base = fm4 + ((size_t)(b * FH) * FW) * 64 + lane;
  for (int yy = r0; yy < r1; ++yy) {
    const float4* rowp = base + (size_t)(yy * FW) * 64;
    for (int xx = c0; xx < c1; ++xx) {
      float4 v = rowp[(size_t)xx * 64];
      m.x = fmaxf(m.x, v.x);
      m.y = fmaxf(m.y, v.y);
      m.z = fmaxf(m.z, v.z);
      m.w = fmaxf(m.w, v.w);
    }
  }

  out4[(size_t)obin * 64 + lane] = m;
}

extern "C" void kernel_launch(void* const* d_in, const int* in_sizes, int n_in,
                              void* d_out, int out_size, void* d_ws, size_t ws_size,
                              hipStream_t stream) {
  const float4* fm4 = (const float4*)d_in[0];
  const float* rois = (const float*)d_in[1];
  float4* out4 = (float4*)d_out;
  const int nblocks = (NBINS + 3) / 4;  // 1176
  roi_pool_kernel<<<nblocks, 256, 0, stream>>>(fm4, rois, out4);
}

// Round 3
// 19.783 us; speedup vs baseline: 1.1086x; 1.0352x over previous
//
#include <hip/hip_runtime.h>
#include <math.h>

// RoI pooling: fm [2,56,56,256] f32, rois [2,48,4] f32 (x, y_max, w, h),
// out [2,48,7,7,256] f32.
//
// One WAVE per output bin; lane l holds channels 4l..4l+3 as a float4
// (global_load_dwordx4, 1 KB/wave coalesced). 4 bins per 256-thread block.
// Bin index forced wave-uniform via readfirstlane so roi load is
// s_load_dwordx4 and all geometry/loop bounds live on the SALU.

#define NB 2
#define NR 48
#define FH 56
#define FW 56
#define NC 256
#define PH 7
#define PW 7
#define NBINS (NB * NR * PH * PW)   // 4704 = 1176 blocks * 4 waves exactly

__global__ __launch_bounds__(256) void roi_pool_kernel(
    const float4* __restrict__ fm4, const float* __restrict__ rois,
    float4* __restrict__ out4) {
  const int lane = threadIdx.x & 63;          // channel group (4 ch each)
  // Wave-uniform bin id -> SGPR; geometry becomes SALU + s_load.
  int bin = __builtin_amdgcn_readfirstlane(blockIdx.x * 4 + (threadIdx.x >> 6));
  const int obin = bin;

  const int j = bin % PW; bin /= PW;
  const int i = bin % PH; bin /= PH;
  const int r = bin % NR;
  const int b = bin / NR;

  const float* roi = rois + (b * NR + r) * 4;
  const float x = roi[0], y = roi[1], w = roi[2], h = roi[3];

  // Match JAX reference fp32 arithmetic + trunc-to-int32 exactly.
  const int w_start = (int)(56.0f * x);
  const int w_end   = (int)(56.0f * (x + w));
  const int h_start = (int)(56.0f * (1.0f - y));
  const int h_end   = (int)(56.0f * (1.0f - y + h));
  const int rh = h_end - h_start;
  const int rw = w_end - w_start;
  const int h_step = rh / PH;
  const int w_step = rw / PW;

  const int r0 = h_start + i * h_step;
  const int r1 = (i == PH - 1) ? (h_start + rh) : (r0 + h_step);
  const int c0 = w_start + j * w_step;
  const int c1 = (j == PW - 1) ? (w_start + rw) : (c0 + w_step);

  // fm4 layout: [(b*FH + y)*FW + x] * 64 + lane  (64 float4 per pixel)
  float4 m = make_float4(-INFINITY, -INFINITY, -INFINITY, -INFINITY);
  const float4* base = fm4 + ((size_t)(b * FH) * FW) * 64 + lane;
  for (int yy = r0; yy < r1; ++yy) {
    const float4* rowp = base + (size_t)(yy * FW) * 64;
    for (int xx = c0; xx < c1; ++xx) {
      float4 v = rowp[(size_t)xx * 64];
      m.x = fmaxf(m.x, v.x);
      m.y = fmaxf(m.y, v.y);
      m.z = fmaxf(m.z, v.z);
      m.w = fmaxf(m.w, v.w);
    }
  }

  out4[(size_t)obin * 64 + lane] = m;
}

extern "C" void kernel_launch(void* const* d_in, const int* in_sizes, int n_in,
                              void* d_out, int out_size, void* d_ws, size_t ws_size,
                              hipStream_t stream) {
  const float4* fm4 = (const float4*)d_in[0];
  const float* rois = (const float*)d_in[1];
  float4* out4 = (float4*)d_out;
  roi_pool_kernel<<<NBINS / 4, 256, 0, stream>>>(fm4, rois, out4);
}